// Round 15
// baseline (189.989 us; speedup 1.0000x reference)
//
#include <hip/hip_runtime.h>

#define WS 9
#define PS 7
#define KMAX 10
#define STRIDE0 4
#define NEPOCHS 100
#define BB 1
#define TT 5
#define CC 3
#define HH 256
#define WW 256
#define QQ (TT * 64 * 64)             // 20480
#define NOFF 243
#define SELF_IDX 40                   // (WS/2)*WS + WS/2
#define HW (HH * WW)

typedef float f4a __attribute__((ext_vector_type(4)));              // aligned LDS/reg
typedef float f4u __attribute__((ext_vector_type(4), aligned(4)));  // 4B-aligned global

static __device__ __forceinline__ int k_eff_from_epoch(int ep) {
    int k = (int)((double)KMAX * ((double)(NEPOCHS - ep) / (double)NEPOCHS));
    return k < 2 ? 2 : k;
}

template <int CTRL>
static __device__ __forceinline__ float dpp_add(float v) {
    const int x = __float_as_int(v);
    const int y = __builtin_amdgcn_update_dpp(0, x, CTRL, 0xF, 0xF, true);
    return v + __int_as_float(y);
}
static __device__ __forceinline__ float swz4_add(float v) {
    const int x = __float_as_int(v);
    const int y = __builtin_amdgcn_ds_swizzle(x, 0x101F);   // xor-4, and=0x1F
    return v + __int_as_float(y);
}

// 4 wave-local queries per 256-thread block (R14 skeleton), LDS squeezed to
// 40800B declared (-> 40960 alloc = 4 blocks/CU): tile [9][15][16] per wave
// with XOR quad-swizzle (storage_quad = q ^ (row&3), <=2-way conflicts),
// dpat packed to 147, dists to 243. Staging: 9 plane-rounds with compile-time
// (dti,c), lanes<60 (row=lane>>2, qd=lane&3). Refine: per-k wave-uniform loop
// (readfirstlane candidate, dpat hoisted to 3 regs). Search dists bit-exact
// vs R14 -> identical selection.
__global__ __launch_bounds__(256) void dnls_query_kernel(
    const float* __restrict__ noisy, const float* __restrict__ deno,
    const float* __restrict__ fflow, const float* __restrict__ bflow,
    const int* __restrict__ ep_ptr, float* __restrict__ partial)
{
    const int tid  = threadIdx.x;
    const int wid  = tid >> 6;
    const int lane = tid & 63;
    const int sub  = lane & 7;
    const int q    = blockIdx.x * 4 + wid;
    const int tqi  = q >> 12;
    const int r0   = q & 4095;
    const int hq   = (r0 >> 6) * STRIDE0;
    const int wq   = (r0 & 63) * STRIDE0;
    const int k_eff = k_eff_from_epoch(ep_ptr[0]);

    __shared__ __align__(16) float tile[4][9][15][16];   // 34560 B, quad-swizzled
    __shared__ float dpat[4][147];                       // 2352 B
    __shared__ float dists[4][243];                      // 3888 B

    // --- centers (wave-uniform; flow loads broadcast) ---
    const size_t bfo = (size_t)(tqi * 2) * HW + (size_t)hq * WW + wq;
    const int ifdx = (int)rintf(fflow[bfo]);
    const int ifdy = (int)rintf(fflow[bfo + HW]);
    const int ibdx = (int)rintf(bflow[bfo]);
    const int ibdy = (int)rintf(bflow[bfo + HW]);
    const int tc0 = tqi, tc1 = max(tqi - 1, 0), tc2 = min(tqi + 1, TT - 1);
    const int hv0 = hq, hv1 = min(max(hq + ibdy, 0), HH - 1), hv2 = min(max(hq + ifdy, 0), HH - 1);
    const int wv0 = wq, wv1 = min(max(wq + ibdx, 0), WW - 1), wv2 = min(max(wq + ifdx, 0), WW - 1);

    // --- staging: 9 plane-rounds, compile-time (dti,c); 60 lanes/round ---
    #pragma unroll
    for (int p = 0; p < 9; ++p) {
        const int dti = p / 3, c = p - dti * 3;        // compile-time
        const int tcv = dti == 0 ? tc0 : (dti == 1 ? tc1 : tc2);
        const int hcv = dti == 0 ? hv0 : (dti == 1 ? hv1 : hv2);
        const int wcv = dti == 0 ? wv0 : (dti == 1 ? wv1 : wv2);
        const int h0  = max(hcv - 4, 0), w0 = max(wcv - 4, 0);
        if (lane < 60) {
            const int row = lane >> 2, qd = lane & 3;
            const int sq  = qd ^ (row & 3);            // storage quad (XOR swizzle)
            const float* src = noisy + (size_t)(tcv * CC + c) * HW;
            f4a v;
            if (hcv <= HH - 11 && wcv <= WW - 12) {    // wave-uniform per plane
                v = (f4a)(*(const f4u*)(src + (h0 + row) * WW + w0 + qd * 4));
            } else {
                const int rrow = min(h0 + row, HH - 1);
                const float* sr = src + rrow * WW;
                #pragma unroll
                for (int t = 0; t < 4; ++t)
                    v[t] = sr[min(w0 + min(qd * 4 + t, 14), WW - 1)];
            }
            *(f4a*)&tile[wid][p][row][sq * 4] = v;
        }
    }
    // --- dpat staging: 147 floats packed [c*49 + i*7 + j] ---
    #pragma unroll
    for (int rr = 0; rr < 3; ++rr) {
        const int u = lane + rr * 64;
        if (u < 147) {
            const int c = u / 49, ij = u - c * 49, i = ij / 7, j = ij - (ij / 7) * 7;
            dpat[wid][u] = deno[(size_t)(tqi * CC + c) * HW
                           + min(hq + i, HH - 1) * WW + min(wq + j, WW - 1)];
        }
    }
    __builtin_amdgcn_wave_barrier();   // order staging ds_writes before ds_reads

    // --- qv hoist: query row (i = sub) from tile[wid][0..2] (dti=0 planes) ---
    const int oh = min(hq, 4), ow = min(wq, 4);
    float qv[CC][8];
    {
        const int r  = oh + sub;                       // <= 11, in bounds
        const int sw = r & 3;
        const int q0 = ow >> 2;                        // 0 or 1 (wq%4==0)
        #pragma unroll
        for (int c = 0; c < CC; ++c) {
            *(f4a*)&qv[c][0] = *(const f4a*)&tile[wid][c][r][(q0 ^ sw) * 4];
            *(f4a*)&qv[c][4] = *(const f4a*)&tile[wid][c][r][((q0 + 1) ^ sw) * 4];
        }
    }

    // --- search: 4 iterations x 8 groups; g=(dti,dh), lane sub = patch row i ---
    #pragma unroll
    for (int it = 0; it < 4; ++it) {
        const int g = it * 8 + (lane >> 3);
        if (g < 27) {
            const int dti = (g >= 18) ? 2 : (g >= 9 ? 1 : 0);
            const int dh  = g - 9 * dti;
            const int hcv = dti == 0 ? hv0 : (dti == 1 ? hv1 : hv2);
            const int wcv = dti == 0 ? wv0 : (dti == 1 ? wv1 : wv2);
            float acc[9];
            #pragma unroll
            for (int dw = 0; dw < 9; ++dw) acc[dw] = 0.f;
            if (sub < PS) {
                if (hcv >= 4 && wcv >= 4) {
                    // fast path: staged clamps exact; r = dh+i, cols = dw+j
                    const int r  = dh + sub;
                    const int sw = r & 3;
                    #pragma unroll
                    for (int c = 0; c < CC; ++c) {
                        const float* tp = &tile[wid][dti * 3 + c][r][0];
                        float tv[16];
                        *(f4a*)&tv[0]  = *(const f4a*)(tp + ((0 ^ sw) << 2));
                        *(f4a*)&tv[4]  = *(const f4a*)(tp + ((1 ^ sw) << 2));
                        *(f4a*)&tv[8]  = *(const f4a*)(tp + ((2 ^ sw) << 2));
                        *(f4a*)&tv[12] = *(const f4a*)(tp + ((3 ^ sw) << 2));
                        #pragma unroll
                        for (int dw = 0; dw < 9; ++dw) {
                            #pragma unroll
                            for (int j = 0; j < 7; ++j) {
                                const float d = qv[c][j] - tv[dw + j];
                                acc[dw] = fmaf(d, d, acc[dw]);
                            }
                        }
                    }
                } else {
                    // top/left-edge centers: double clamp mapped into the tile
                    const int h0 = max(hcv - 4, 0), w0 = max(wcv - 4, 0);
                    const int hc = min(max(hcv + dh - 4, 0), HH - 1);
                    const int r  = min(hc + sub, HH - 1) - h0;
                    const int swb = (r & 3) << 2;
                    #pragma unroll
                    for (int c = 0; c < CC; ++c) {
                        const float* tp = &tile[wid][dti * 3 + c][r][0];
                        #pragma unroll
                        for (int dw = 0; dw < 9; ++dw) {
                            const int wc = min(max(wcv + dw - 4, 0), WW - 1);
                            #pragma unroll
                            for (int j = 0; j < 7; ++j) {
                                const int col = min(wc + j, WW - 1) - w0;
                                const float d = qv[c][j] - tp[col ^ swb];
                                acc[dw] = fmaf(d, d, acc[dw]);
                            }
                        }
                    }
                }
            }
            // sum the 7 rows across the 8-lane segment (same tree as __shfl_xor)
            #pragma unroll
            for (int dw = 0; dw < 9; ++dw) {
                float v = acc[dw];
                v = dpp_add<0xB1>(v);   // xor 1
                v = dpp_add<0x4E>(v);   // xor 2
                v = swz4_add(v);        // xor 4
                acc[dw] = v;
            }
            if (sub == 0) {
                #pragma unroll
                for (int dw = 0; dw < 9; ++dw) dists[wid][g * 9 + dw] = acc[dw];
            }
        }
    }
    __builtin_amdgcn_wave_barrier();   // order dist writes before reads

    // --- in-register top-k (strict <, lowest-index tie-break) ---
    const float* dq = dists[wid];
    float dv[4]; int dn[4];
    #pragma unroll
    for (int kk = 0; kk < 4; ++kk) {
        const int n = lane + kk * 64;
        float v = (n < NOFF) ? dq[n] : INFINITY;
        if (n == SELF_IDX) v = -INFINITY;
        dv[kk] = v; dn[kk] = n;
    }
    int seln[KMAX];
    #pragma unroll
    for (int k = 0; k < KMAX; ++k) {
        float bv = dv[0]; int bi = dn[0];
        #pragma unroll
        for (int kk = 1; kk < 4; ++kk)
            if (dv[kk] < bv || (dv[kk] == bv && dn[kk] < bi)) { bv = dv[kk]; bi = dn[kk]; }
        #pragma unroll
        for (int off = 32; off > 0; off >>= 1) {
            const float ov = __shfl_xor(bv, off);
            const int   oi = __shfl_xor(bi, off);
            if (ov < bv || (ov == bv && oi < bi)) { bv = ov; bi = oi; }
        }
        seln[k] = bi;
        #pragma unroll
        for (int kk = 0; kk < 4; ++kk) if (dn[kk] == bi) dv[kk] = INFINITY;
    }

    // --- refine: per-k wave-uniform loop; lanes 0..48 = (i,j) of the patch ---
    const int li = lane / 7, lj = lane - (lane / 7) * 7;   // valid for lane<49
    float dpr[CC];
    #pragma unroll
    for (int c = 0; c < CC; ++c) dpr[c] = (lane < 49) ? dpat[wid][c * 49 + lane] : 0.f;
    float part = 0.f;
    #pragma unroll
    for (int k = 1; k < KMAX; ++k) {
        if (k < k_eff) {
            const int n = __builtin_amdgcn_readfirstlane(seln[k]);  // wave-uniform
            const int dti = (n >= 162) ? 2 : (n >= 81 ? 1 : 0);
            const int rr  = n - dti * 81;
            const int dh  = rr / 9;
            const int dw  = rr - dh * 9;
            const int hcv = dti == 0 ? hv0 : (dti == 1 ? hv1 : hv2);
            const int wcv = dti == 0 ? wv0 : (dti == 1 ? wv1 : wv2);
            const int h0  = max(hcv - 4, 0), w0 = max(wcv - 4, 0);
            const int hc  = min(max(hcv + dh - 4, 0), HH - 1);
            const int wc  = min(max(wcv + dw - 4, 0), WW - 1);
            if (lane < 49) {
                const int row = min(hc + li, HH - 1) - h0;
                const int col = min(wc + lj, WW - 1) - w0;
                const int sc  = col ^ ((row & 3) << 2);
                #pragma unroll
                for (int c = 0; c < CC; ++c) {
                    const float d = dpr[c] - tile[wid][dti * 3 + c][row][sc];
                    part = fmaf(d, d, part);
                }
            }
        }
    }

    #pragma unroll
    for (int off = 32; off > 0; off >>= 1) part += __shfl_xor(part, off);
    if (lane == 0) partial[q] = part;
}

__global__ __launch_bounds__(1024) void dnls_reduce_kernel(
    const float* __restrict__ partial, int n,
    const int* __restrict__ ep_ptr, float* __restrict__ out)
{
    const int tid = threadIdx.x;
    double acc = 0.0;
    for (int i = tid; i < n; i += 1024) acc += (double)partial[i];
    __shared__ double red[1024];
    red[tid] = acc;
    __syncthreads();
    for (int s = 512; s > 0; s >>= 1) {
        if (tid < s) red[tid] += red[tid + s];
        __syncthreads();
    }
    if (tid == 0) {
        const int k_eff = k_eff_from_epoch(ep_ptr[0]);
        out[0] = (float)(red[0] / ((double)n * (double)(k_eff - 1)));
    }
}

extern "C" void kernel_launch(void* const* d_in, const int* in_sizes, int n_in,
                              void* d_out, int out_size, void* d_ws, size_t ws_size,
                              hipStream_t stream) {
    const float* noisy = (const float*)d_in[0];
    const float* deno  = (const float*)d_in[1];
    const float* fflow = (const float*)d_in[2];
    const float* bflow = (const float*)d_in[3];
    const int*   ep    = (const int*)d_in[4];
    float* partial = (float*)d_ws;            // BB*QQ floats = 80 KB
    float* out = (float*)d_out;

    dnls_query_kernel<<<(BB * QQ) / 4, 256, 0, stream>>>(noisy, deno, fflow, bflow, ep, partial);
    dnls_reduce_kernel<<<1, 1024, 0, stream>>>(partial, BB * QQ, ep, out);
}

// Round 16
// 132.643 us; speedup vs baseline: 1.4323x; 1.4323x over previous
//
#include <hip/hip_runtime.h>

#define WS 9
#define PS 7
#define KMAX 10
#define STRIDE0 4
#define NEPOCHS 100
#define BB 1
#define TT 5
#define CC 3
#define HH 256
#define WW 256
#define QQ (TT * 64 * 64)             // 20480
#define NOFF 243
#define SELF_IDX 40                   // (WS/2)*WS + WS/2
#define HW (HH * WW)
#define TSTR 20                       // tile row stride: 80B = b128-aligned

typedef float f4a __attribute__((ext_vector_type(4)));              // aligned LDS/reg
typedef float f4u __attribute__((ext_vector_type(4), aligned(4)));  // 4B-aligned global
typedef float f2  __attribute__((ext_vector_type(2)));              // packed pair

static __device__ __forceinline__ int k_eff_from_epoch(int ep) {
    int k = (int)((double)KMAX * ((double)(NEPOCHS - ep) / (double)NEPOCHS));
    return k < 2 ? 2 : k;
}

template <int CTRL>
static __device__ __forceinline__ float dpp_add(float v) {
    const int x = __float_as_int(v);
    const int y = __builtin_amdgcn_update_dpp(0, x, CTRL, 0xF, 0xF, true);
    return v + __int_as_float(y);
}
static __device__ __forceinline__ float swz4_add(float v) {
    const int x = __float_as_int(v);
    const int y = __builtin_amdgcn_ds_swizzle(x, 0x101F);   // xor-4, and=0x1F
    return v + __int_as_float(y);
}

// R14 skeleton: 4 wave-local queries per 256-thread block, zero __syncthreads,
// TSTR=20 plain addressing. R16 deltas: (1) search fast path packed as float2
// dw-pairs -> v_pk_fma_f32 (per-half IEEE == scalar fmaf, distances bit-exact);
// (2) dpat removed — refine lanes load their 3 deno values straight to regs at
// staging time; refine is the wave-uniform per-k loop (verified in R15).
__global__ __launch_bounds__(256) void dnls_query_kernel(
    const float* __restrict__ noisy, const float* __restrict__ deno,
    const float* __restrict__ fflow, const float* __restrict__ bflow,
    const int* __restrict__ ep_ptr, float* __restrict__ partial)
{
    const int tid  = threadIdx.x;
    const int wid  = tid >> 6;
    const int lane = tid & 63;
    const int sub  = lane & 7;
    const int q    = blockIdx.x * 4 + wid;
    const int tqi  = q >> 12;
    const int r0   = q & 4095;
    const int hq   = (r0 >> 6) * STRIDE0;
    const int wq   = (r0 & 63) * STRIDE0;
    const int k_eff = k_eff_from_epoch(ep_ptr[0]);

    __shared__ __align__(16) float tile[4][3][CC][15][TSTR];   // 43.2 KB
    __shared__ float dists[4][243];                            // 3.9 KB

    // --- centers (wave-uniform; flow loads broadcast) ---
    const size_t bfo = (size_t)(tqi * 2) * HW + (size_t)hq * WW + wq;
    const int ifdx = (int)rintf(fflow[bfo]);
    const int ifdy = (int)rintf(fflow[bfo + HW]);
    const int ibdx = (int)rintf(bflow[bfo]);
    const int ibdy = (int)rintf(bflow[bfo + HW]);
    const int tc0 = tqi, tc1 = max(tqi - 1, 0), tc2 = min(tqi + 1, TT - 1);
    const int hv0 = hq, hv1 = min(max(hq + ibdy, 0), HH - 1), hv2 = min(max(hq + ifdy, 0), HH - 1);
    const int wv0 = wq, wv1 = min(max(wq + ibdx, 0), WW - 1), wv2 = min(max(wq + ifdx, 0), WW - 1);

    // --- refine deno values straight to registers (consumed at the very end) ---
    const int li = lane / 7, lj = lane - (lane / 7) * 7;   // valid for lane<49
    float dpr[CC];
    {
        const float* db = deno + (size_t)(tqi * CC) * HW
                          + (size_t)min(hq + li, HH - 1) * WW + min(wq + lj, WW - 1);
        #pragma unroll
        for (int c = 0; c < CC; ++c) dpr[c] = (lane < 49) ? db[c * HW] : 0.f;
    }

    // --- per-wave tile staging: 540 b128 quads over 64 lanes, 9 rounds ---
    #pragma unroll
    for (int rr = 0; rr < 9; ++rr) {
        const int u = lane + rr * 64;
        if (u < 540) {
            const int p   = u / 60;
            const int rem = u - p * 60;
            const int row = rem >> 2, qd = rem & 3;
            const int dti = (p >= 6) ? 2 : (p >= 3 ? 1 : 0);
            const int c   = p - dti * 3;
            const int tcv = dti == 0 ? tc0 : (dti == 1 ? tc1 : tc2);
            const int hcv = dti == 0 ? hv0 : (dti == 1 ? hv1 : hv2);
            const int wcv = dti == 0 ? wv0 : (dti == 1 ? wv1 : wv2);
            const int h0  = max(hcv - 4, 0), w0 = max(wcv - 4, 0);
            const float* src = noisy + (size_t)(tcv * CC + c) * HW;
            f4a v;
            if (hcv <= HH - 11 && wcv <= WW - 12) {
                v = (f4a)(*(const f4u*)(src + (h0 + row) * WW + w0 + qd * 4));
            } else {
                const int rrow = min(h0 + row, HH - 1);
                const float* sr = src + rrow * WW;
                #pragma unroll
                for (int t = 0; t < 4; ++t)
                    v[t] = sr[min(w0 + min(qd * 4 + t, 14), WW - 1)];
            }
            *(f4a*)&tile[wid][dti][c][row][qd * 4] = v;
        }
    }
    __builtin_amdgcn_wave_barrier();   // order staging ds_writes before ds_reads

    // --- qv hoist: query patch row (i = sub) from tile[wid][0], bit-exact ---
    const int oh = min(hq, 4), ow = min(wq, 4);
    float qv[CC][8];
    #pragma unroll
    for (int c = 0; c < CC; ++c) {
        *(f4a*)&qv[c][0] = *(const f4a*)&tile[wid][0][c][oh + sub][ow];
        *(f4a*)&qv[c][4] = *(const f4a*)&tile[wid][0][c][oh + sub][ow + 4];
    }

    // --- search: 4 iterations x 8 groups; g=(dti,dh), lane sub = patch row i ---
    #pragma unroll
    for (int it = 0; it < 4; ++it) {
        const int g = it * 8 + (lane >> 3);
        if (g < 27) {
            const int dti = (g >= 18) ? 2 : (g >= 9 ? 1 : 0);
            const int dh  = g - 9 * dti;
            const int hcv = dti == 0 ? hv0 : (dti == 1 ? hv1 : hv2);
            const int wcv = dti == 0 ? wv0 : (dti == 1 ? wv1 : wv2);
            float acc[9];
            #pragma unroll
            for (int dw = 0; dw < 9; ++dw) acc[dw] = 0.f;
            if (sub < PS) {
                if (hcv >= 4 && wcv >= 4) {
                    // fast path, pk-packed: dw pairs (0,1)(2,3)(4,5)(6,7) + dw=8
                    const int r = dh + sub;
                    f2 a2[4] = { f2{0.f,0.f}, f2{0.f,0.f}, f2{0.f,0.f}, f2{0.f,0.f} };
                    float a8 = 0.f;
                    #pragma unroll
                    for (int c = 0; c < CC; ++c) {
                        float tv[16];
                        *(f4a*)&tv[0]  = *(const f4a*)&tile[wid][dti][c][r][0];
                        *(f4a*)&tv[4]  = *(const f4a*)&tile[wid][dti][c][r][4];
                        *(f4a*)&tv[8]  = *(const f4a*)&tile[wid][dti][c][r][8];
                        *(f4a*)&tv[12] = *(const f4a*)&tile[wid][dti][c][r][12];
                        #pragma unroll
                        for (int j = 0; j < 7; ++j) {
                            const float qj = qv[c][j];
                            #pragma unroll
                            for (int p = 0; p < 4; ++p) {
                                f2 t; t[0] = tv[2 * p + j]; t[1] = tv[2 * p + 1 + j];
                                const f2 d = qj - t;                 // v_pk_add (neg)
                                a2[p] = __builtin_elementwise_fma(d, d, a2[p]);  // v_pk_fma
                            }
                            const float ds = qj - tv[8 + j];
                            a8 = fmaf(ds, ds, a8);
                        }
                    }
                    #pragma unroll
                    for (int p = 0; p < 4; ++p) { acc[2 * p] = a2[p][0]; acc[2 * p + 1] = a2[p][1]; }
                    acc[8] = a8;
                } else {
                    // top/left-edge centers: double clamp mapped into the tile
                    const int h0 = max(hcv - 4, 0), w0 = max(wcv - 4, 0);
                    const int hc = min(max(hcv + dh - 4, 0), HH - 1);
                    const int r  = min(hc + sub, HH - 1) - h0;
                    #pragma unroll
                    for (int c = 0; c < CC; ++c) {
                        #pragma unroll
                        for (int dw = 0; dw < 9; ++dw) {
                            const int wc = min(max(wcv + dw - 4, 0), WW - 1);
                            #pragma unroll
                            for (int j = 0; j < 7; ++j) {
                                const int col = min(wc + j, WW - 1) - w0;
                                const float d = qv[c][j] - tile[wid][dti][c][r][col];
                                acc[dw] = fmaf(d, d, acc[dw]);
                            }
                        }
                    }
                }
            }
            // sum the 7 rows across the 8-lane segment (same tree as __shfl_xor)
            #pragma unroll
            for (int dw = 0; dw < 9; ++dw) {
                float v = acc[dw];
                v = dpp_add<0xB1>(v);   // xor 1
                v = dpp_add<0x4E>(v);   // xor 2
                v = swz4_add(v);        // xor 4
                acc[dw] = v;
            }
            if (sub == 0) {
                #pragma unroll
                for (int dw = 0; dw < 9; ++dw) dists[wid][g * 9 + dw] = acc[dw];
            }
        }
    }
    __builtin_amdgcn_wave_barrier();   // order dist writes before reads

    // --- in-register top-k (strict <, lowest-index tie-break) ---
    const float* dq = dists[wid];
    float dv[4]; int dn[4];
    #pragma unroll
    for (int kk = 0; kk < 4; ++kk) {
        const int n = lane + kk * 64;
        float v = (n < NOFF) ? dq[n] : INFINITY;
        if (n == SELF_IDX) v = -INFINITY;
        dv[kk] = v; dn[kk] = n;
    }
    int seln[KMAX];
    #pragma unroll
    for (int k = 0; k < KMAX; ++k) {
        float bv = dv[0]; int bi = dn[0];
        #pragma unroll
        for (int kk = 1; kk < 4; ++kk)
            if (dv[kk] < bv || (dv[kk] == bv && dn[kk] < bi)) { bv = dv[kk]; bi = dn[kk]; }
        #pragma unroll
        for (int off = 32; off > 0; off >>= 1) {
            const float ov = __shfl_xor(bv, off);
            const int   oi = __shfl_xor(bi, off);
            if (ov < bv || (ov == bv && oi < bi)) { bv = ov; bi = oi; }
        }
        seln[k] = bi;
        #pragma unroll
        for (int kk = 0; kk < 4; ++kk) if (dn[kk] == bi) dv[kk] = INFINITY;
    }

    // --- refine: per-k wave-uniform loop; lanes 0..48 = (i,j) of the patch ---
    float part = 0.f;
    #pragma unroll
    for (int k = 1; k < KMAX; ++k) {
        if (k < k_eff) {
            const int n = __builtin_amdgcn_readfirstlane(seln[k]);  // wave-uniform
            const int dti = (n >= 162) ? 2 : (n >= 81 ? 1 : 0);
            const int rr  = n - dti * 81;
            const int dh  = rr / 9;
            const int dw  = rr - dh * 9;
            const int hcv = dti == 0 ? hv0 : (dti == 1 ? hv1 : hv2);
            const int wcv = dti == 0 ? wv0 : (dti == 1 ? wv1 : wv2);
            const int h0  = max(hcv - 4, 0), w0 = max(wcv - 4, 0);
            const int hc  = min(max(hcv + dh - 4, 0), HH - 1);
            const int wc  = min(max(wcv + dw - 4, 0), WW - 1);
            if (lane < 49) {
                const int row = min(hc + li, HH - 1) - h0;
                const int col = min(wc + lj, WW - 1) - w0;
                #pragma unroll
                for (int c = 0; c < CC; ++c) {
                    const float d = dpr[c] - tile[wid][dti][c][row][col];
                    part = fmaf(d, d, part);
                }
            }
        }
    }

    #pragma unroll
    for (int off = 32; off > 0; off >>= 1) part += __shfl_xor(part, off);
    if (lane == 0) partial[q] = part;
}

__global__ __launch_bounds__(1024) void dnls_reduce_kernel(
    const float* __restrict__ partial, int n,
    const int* __restrict__ ep_ptr, float* __restrict__ out)
{
    const int tid = threadIdx.x;
    double acc = 0.0;
    for (int i = tid; i < n; i += 1024) acc += (double)partial[i];
    __shared__ double red[1024];
    red[tid] = acc;
    __syncthreads();
    for (int s = 512; s > 0; s >>= 1) {
        if (tid < s) red[tid] += red[tid + s];
        __syncthreads();
    }
    if (tid == 0) {
        const int k_eff = k_eff_from_epoch(ep_ptr[0]);
        out[0] = (float)(red[0] / ((double)n * (double)(k_eff - 1)));
    }
}

extern "C" void kernel_launch(void* const* d_in, const int* in_sizes, int n_in,
                              void* d_out, int out_size, void* d_ws, size_t ws_size,
                              hipStream_t stream) {
    const float* noisy = (const float*)d_in[0];
    const float* deno  = (const float*)d_in[1];
    const float* fflow = (const float*)d_in[2];
    const float* bflow = (const float*)d_in[3];
    const int*   ep    = (const int*)d_in[4];
    float* partial = (float*)d_ws;            // BB*QQ floats = 80 KB
    float* out = (float*)d_out;

    dnls_query_kernel<<<(BB * QQ) / 4, 256, 0, stream>>>(noisy, deno, fflow, bflow, ep, partial);
    dnls_reduce_kernel<<<1, 1024, 0, stream>>>(partial, BB * QQ, ep, out);
}

// Round 17
// 116.064 us; speedup vs baseline: 1.6369x; 1.1428x over previous
//
#include <hip/hip_runtime.h>

#define WS 9
#define PS 7
#define KMAX 10
#define STRIDE0 4
#define NEPOCHS 100
#define BB 1
#define TT 5
#define CC 3
#define HH 256
#define WW 256
#define QQ (TT * 64 * 64)             // 20480
#define NOFF 243
#define SELF_IDX 40                   // (WS/2)*WS + WS/2
#define HW (HH * WW)
#define TSTR 20                       // tile row stride: 80B = b128-aligned, conflict-free

typedef float f4a __attribute__((ext_vector_type(4)));              // aligned LDS/reg
typedef float f4u __attribute__((ext_vector_type(4), aligned(4)));  // 4B-aligned global
typedef float f2  __attribute__((ext_vector_type(2)));              // packed pair
typedef long long s64;

static __device__ __forceinline__ int k_eff_from_epoch(int ep) {
    int k = (int)((double)KMAX * ((double)(NEPOCHS - ep) / (double)NEPOCHS));
    return k < 2 ? 2 : k;
}

template <int CTRL>
static __device__ __forceinline__ float dpp_add(float v) {
    const int x = __float_as_int(v);
    const int y = __builtin_amdgcn_update_dpp(0, x, CTRL, 0xF, 0xF, true);
    return v + __int_as_float(y);
}
static __device__ __forceinline__ float swz4_add(float v) {
    const int x = __float_as_int(v);
    const int y = __builtin_amdgcn_ds_swizzle(x, 0x101F);   // xor-4, and=0x1F
    return v + __int_as_float(y);
}

// R16 skeleton (4 wave-local queries / 256-thread block, zero __syncthreads,
// TSTR=20, pk-packed search, refine data in regs). R17 deltas:
// (1) staging = 9 plane-rounds with COMPILE-TIME (dti,c): plane constants fold,
//     row/qd from lane bits, lanes>=60 idle — same addresses, no swizzle;
// (2) top-k on packed s64 keys ((s64)float_bits<<32 | n): signed-64 ordering
//     == (dist, idx) lex order bit-exactly (dists >= 0; -inf self anchor sorts
//     first; equal floats have equal bits; low word breaks ties to lower n).
__global__ __launch_bounds__(256) void dnls_query_kernel(
    const float* __restrict__ noisy, const float* __restrict__ deno,
    const float* __restrict__ fflow, const float* __restrict__ bflow,
    const int* __restrict__ ep_ptr, float* __restrict__ partial)
{
    const int tid  = threadIdx.x;
    const int wid  = tid >> 6;
    const int lane = tid & 63;
    const int sub  = lane & 7;
    const int q    = blockIdx.x * 4 + wid;
    const int tqi  = q >> 12;
    const int r0   = q & 4095;
    const int hq   = (r0 >> 6) * STRIDE0;
    const int wq   = (r0 & 63) * STRIDE0;
    const int k_eff = k_eff_from_epoch(ep_ptr[0]);

    __shared__ __align__(16) float tile[4][9][15][TSTR];   // 43.2 KB ([dti*3+c] planes)
    __shared__ float dists[4][243];                        // 3.9 KB

    // --- centers (wave-uniform; flow loads broadcast) ---
    const size_t bfo = (size_t)(tqi * 2) * HW + (size_t)hq * WW + wq;
    const int ifdx = (int)rintf(fflow[bfo]);
    const int ifdy = (int)rintf(fflow[bfo + HW]);
    const int ibdx = (int)rintf(bflow[bfo]);
    const int ibdy = (int)rintf(bflow[bfo + HW]);
    const int tcA[3] = { tqi, max(tqi - 1, 0), min(tqi + 1, TT - 1) };
    const int hvA[3] = { hq, min(max(hq + ibdy, 0), HH - 1), min(max(hq + ifdy, 0), HH - 1) };
    const int wvA[3] = { wq, min(max(wq + ibdx, 0), WW - 1), min(max(wq + ifdx, 0), WW - 1) };

    // --- refine deno values straight to registers (consumed at the very end) ---
    const int li = lane / 7, lj = lane - (lane / 7) * 7;   // valid for lane<49
    float dpr[CC];
    {
        const float* db = deno + (size_t)(tqi * CC) * HW
                          + (size_t)min(hq + li, HH - 1) * WW + min(wq + lj, WW - 1);
        #pragma unroll
        for (int c = 0; c < CC; ++c) dpr[c] = (lane < 49) ? db[c * HW] : 0.f;
    }

    // --- staging: 9 plane-rounds, compile-time (dti,c); lanes<60 ---
    #pragma unroll
    for (int p = 0; p < 9; ++p) {
        const int dti = p / 3, c = p - dti * 3;            // compile-time
        const int tcv = tcA[dti], hcv = hvA[dti], wcv = wvA[dti];
        const int h0  = max(hcv - 4, 0), w0 = max(wcv - 4, 0);
        if (lane < 60) {
            const int row = lane >> 2, qd = lane & 3;
            const float* src = noisy + (size_t)(tcv * CC + c) * HW;
            f4a v;
            if (hcv <= HH - 11 && wcv <= WW - 12) {        // wave-uniform per plane
                v = (f4a)(*(const f4u*)(src + (h0 + row) * WW + w0 + qd * 4));
            } else {
                const int rrow = min(h0 + row, HH - 1);
                const float* sr = src + rrow * WW;
                #pragma unroll
                for (int t = 0; t < 4; ++t)
                    v[t] = sr[min(w0 + min(qd * 4 + t, 14), WW - 1)];
            }
            *(f4a*)&tile[wid][p][row][qd * 4] = v;
        }
    }
    __builtin_amdgcn_wave_barrier();   // order staging ds_writes before ds_reads

    // --- qv hoist: query patch row (i = sub) from tile[wid][0..2], bit-exact ---
    const int oh = min(hq, 4), ow = min(wq, 4);
    float qv[CC][8];
    #pragma unroll
    for (int c = 0; c < CC; ++c) {
        *(f4a*)&qv[c][0] = *(const f4a*)&tile[wid][c][oh + sub][ow];
        *(f4a*)&qv[c][4] = *(const f4a*)&tile[wid][c][oh + sub][ow + 4];
    }

    // --- search: 4 iterations x 8 groups; g=(dti,dh), lane sub = patch row i ---
    #pragma unroll
    for (int it = 0; it < 4; ++it) {
        const int g = it * 8 + (lane >> 3);
        if (g < 27) {
            const int dti = (g >= 18) ? 2 : (g >= 9 ? 1 : 0);
            const int dh  = g - 9 * dti;
            const int hcv = hvA[dti], wcv = wvA[dti];
            float acc[9];
            #pragma unroll
            for (int dw = 0; dw < 9; ++dw) acc[dw] = 0.f;
            if (sub < PS) {
                if (hcv >= 4 && wcv >= 4) {
                    // fast path, pk-packed: dw pairs (0,1)(2,3)(4,5)(6,7) + dw=8
                    const int r = dh + sub;
                    f2 a2[4] = { f2{0.f,0.f}, f2{0.f,0.f}, f2{0.f,0.f}, f2{0.f,0.f} };
                    float a8 = 0.f;
                    #pragma unroll
                    for (int c = 0; c < CC; ++c) {
                        const float* tp = &tile[wid][dti * 3 + c][r][0];
                        float tv[16];
                        *(f4a*)&tv[0]  = *(const f4a*)(tp);
                        *(f4a*)&tv[4]  = *(const f4a*)(tp + 4);
                        *(f4a*)&tv[8]  = *(const f4a*)(tp + 8);
                        *(f4a*)&tv[12] = *(const f4a*)(tp + 12);
                        #pragma unroll
                        for (int j = 0; j < 7; ++j) {
                            const float qj = qv[c][j];
                            #pragma unroll
                            for (int pp = 0; pp < 4; ++pp) {
                                f2 t; t[0] = tv[2 * pp + j]; t[1] = tv[2 * pp + 1 + j];
                                const f2 d = qj - t;                              // v_pk_add
                                a2[pp] = __builtin_elementwise_fma(d, d, a2[pp]); // v_pk_fma
                            }
                            const float ds = qj - tv[8 + j];
                            a8 = fmaf(ds, ds, a8);
                        }
                    }
                    #pragma unroll
                    for (int pp = 0; pp < 4; ++pp) { acc[2 * pp] = a2[pp][0]; acc[2 * pp + 1] = a2[pp][1]; }
                    acc[8] = a8;
                } else {
                    // top/left-edge centers: double clamp mapped into the tile
                    const int h0 = max(hcv - 4, 0), w0 = max(wcv - 4, 0);
                    const int hc = min(max(hcv + dh - 4, 0), HH - 1);
                    const int r  = min(hc + sub, HH - 1) - h0;
                    #pragma unroll
                    for (int c = 0; c < CC; ++c) {
                        const float* tp = &tile[wid][dti * 3 + c][r][0];
                        #pragma unroll
                        for (int dw = 0; dw < 9; ++dw) {
                            const int wc = min(max(wcv + dw - 4, 0), WW - 1);
                            #pragma unroll
                            for (int j = 0; j < 7; ++j) {
                                const int col = min(wc + j, WW - 1) - w0;
                                const float d = qv[c][j] - tp[col];
                                acc[dw] = fmaf(d, d, acc[dw]);
                            }
                        }
                    }
                }
            }
            // sum the 7 rows across the 8-lane segment (same tree as __shfl_xor)
            #pragma unroll
            for (int dw = 0; dw < 9; ++dw) {
                float v = acc[dw];
                v = dpp_add<0xB1>(v);   // xor 1
                v = dpp_add<0x4E>(v);   // xor 2
                v = swz4_add(v);        // xor 4
                acc[dw] = v;
            }
            if (sub == 0) {
                #pragma unroll
                for (int dw = 0; dw < 9; ++dw) dists[wid][g * 9 + dw] = acc[dw];
            }
        }
    }
    __builtin_amdgcn_wave_barrier();   // order dist writes before reads

    // --- top-k on packed s64 keys (bit-exact (dist, idx) lex order) ---
    const float* dq = dists[wid];
    s64 dk[4];
    #pragma unroll
    for (int kk = 0; kk < 4; ++kk) {
        const int n = lane + kk * 64;
        float v = (n < NOFF) ? dq[n] : INFINITY;
        if (n == SELF_IDX) v = -INFINITY;
        dk[kk] = ((s64)__float_as_int(v) << 32) | (unsigned)n;
    }
    int seln[KMAX];
    #pragma unroll
    for (int k = 0; k < KMAX; ++k) {
        s64 b = dk[0];
        #pragma unroll
        for (int kk = 1; kk < 4; ++kk) if (dk[kk] < b) b = dk[kk];
        #pragma unroll
        for (int off = 32; off > 0; off >>= 1) {
            const s64 o = __shfl_xor(b, off);
            if (o < b) b = o;
        }
        seln[k] = (int)(unsigned)(b & 0xFFFFFFFFll);
        #pragma unroll
        for (int kk = 0; kk < 4; ++kk) if (dk[kk] == b) dk[kk] = 0x7FFFFFFFFFFFFFFFll;
    }

    // --- refine: per-k wave-uniform loop; lanes 0..48 = (i,j) of the patch ---
    float part = 0.f;
    #pragma unroll
    for (int k = 1; k < KMAX; ++k) {
        if (k < k_eff) {
            const int n = __builtin_amdgcn_readfirstlane(seln[k]);  // wave-uniform
            const int dti = (n >= 162) ? 2 : (n >= 81 ? 1 : 0);
            const int rr  = n - dti * 81;
            const int dh  = rr / 9;
            const int dw  = rr - dh * 9;
            const int hcv = hvA[dti], wcv = wvA[dti];
            const int h0  = max(hcv - 4, 0), w0 = max(wcv - 4, 0);
            const int hc  = min(max(hcv + dh - 4, 0), HH - 1);
            const int wc  = min(max(wcv + dw - 4, 0), WW - 1);
            if (lane < 49) {
                const int row = min(hc + li, HH - 1) - h0;
                const int col = min(wc + lj, WW - 1) - w0;
                #pragma unroll
                for (int c = 0; c < CC; ++c) {
                    const float d = dpr[c] - tile[wid][dti * 3 + c][row][col];
                    part = fmaf(d, d, part);
                }
            }
        }
    }

    #pragma unroll
    for (int off = 32; off > 0; off >>= 1) part += __shfl_xor(part, off);
    if (lane == 0) partial[q] = part;
}

__global__ __launch_bounds__(1024) void dnls_reduce_kernel(
    const float* __restrict__ partial, int n,
    const int* __restrict__ ep_ptr, float* __restrict__ out)
{
    const int tid = threadIdx.x;
    double acc = 0.0;
    for (int i = tid; i < n; i += 1024) acc += (double)partial[i];
    __shared__ double red[1024];
    red[tid] = acc;
    __syncthreads();
    for (int s = 512; s > 0; s >>= 1) {
        if (tid < s) red[tid] += red[tid + s];
        __syncthreads();
    }
    if (tid == 0) {
        const int k_eff = k_eff_from_epoch(ep_ptr[0]);
        out[0] = (float)(red[0] / ((double)n * (double)(k_eff - 1)));
    }
}

extern "C" void kernel_launch(void* const* d_in, const int* in_sizes, int n_in,
                              void* d_out, int out_size, void* d_ws, size_t ws_size,
                              hipStream_t stream) {
    const float* noisy = (const float*)d_in[0];
    const float* deno  = (const float*)d_in[1];
    const float* fflow = (const float*)d_in[2];
    const float* bflow = (const float*)d_in[3];
    const int*   ep    = (const int*)d_in[4];
    float* partial = (float*)d_ws;            // BB*QQ floats = 80 KB
    float* out = (float*)d_out;

    dnls_query_kernel<<<(BB * QQ) / 4, 256, 0, stream>>>(noisy, deno, fflow, bflow, ep, partial);
    dnls_reduce_kernel<<<1, 1024, 0, stream>>>(partial, BB * QQ, ep, out);
}